// Round 7
// baseline (1209.175 us; speedup 1.0000x reference)
//
#include <hip/hip_runtime.h>

#define NLAT 721
#define NLON 1440
#define NB 4
#define ND 5
#define NROWS (NLAT*ND)          // 3605
#define PLANE (NLAT*NLON)        // 1,038,240
#define HVOL (NB*PLANE)          // 4,152,960
#define DTSTEP 0.01f
#define TAPCAP 262144
#define TCH 256                  // taps per chunk (multiple of 4)
#define NCOLS 720                // lon columns per block
#define NT 4                     // tap-teams per block
#define TBT 192                  // threads per team (3 waves)
#define BT (NT*TBT)              // 768 block threads
#define ACT 180                  // compute threads per team (x4 cols = 720)
#define SH_SZ (NCOLS + TCH + 8)  // 984 floats per staging array
#define TEAM_F (3*SH_SZ + 4*TCH) // 3976 floats per team slice (15904 B)

// ---- heavy (polar) split: lats 0..11 and 709..720 ----
#define HLO 12                   // l < HLO is heavy (south side: l > 720-HLO)
#define NHL 24                   // heavy lat count
#define HTC 32                   // taps per heavy slice
#define HMAXSL 48                // max slices per lat (l=0 worst: 1440/32=45)
#define ACC_N (NHL*NB*3*NLON)    // accK floats (1.66 MB)

__device__ __forceinline__ bool is_heavy(int l) { return (l < HLO) | (l > NLAT - 1 - HLO); }

// ---------------------------------------------------------------------------
// Kernel A: per (lat,d) row, find the wrapped-interval support [jlo, jhi]
// ---------------------------------------------------------------------------
__global__ __launch_bounds__(64) void support_kernel(
    const float* __restrict__ Kgc, const float* __restrict__ Kgs,
    const float* __restrict__ Kdc, const float* __restrict__ Kds,
    int* __restrict__ jlo_a, int* __restrict__ cnt_a)
{
  int row = blockIdx.x;
  int lane = threadIdx.x;
  const float* a = Kgc + (size_t)row * NLON;
  const float* b = Kgs + (size_t)row * NLON;
  const float* c = Kdc + (size_t)row * NLON;
  const float* d = Kds + (size_t)row * NLON;
  int jmin = 1 << 30, jmax = -(1 << 30);
  for (int m = lane; m < NLON; m += 64) {
    float s = fabsf(a[m]) + fabsf(b[m]) + fabsf(c[m]) + fabsf(d[m]);
    if (s != 0.0f) {
      int j = (m >= NLON / 2) ? (m - NLON) : m;
      jmin = min(jmin, j);
      jmax = max(jmax, j);
    }
  }
  for (int s = 32; s > 0; s >>= 1) {
    jmin = min(jmin, __shfl_down(jmin, s));
    jmax = max(jmax, __shfl_down(jmax, s));
  }
  if (lane == 0) {
    if (jmax < jmin) { jlo_a[row] = 0; cnt_a[row] = 0; }
    else             { jlo_a[row] = jmin; cnt_a[row] = jmax - jmin + 1; }
  }
}

// ---------------------------------------------------------------------------
// Kernel B: prefix sum over 4-padded row counts; per-row meta
// int4(iq*NLON, jlo (signed), cnt4, pool offset).  rowmetaL = same but with
// cnt zeroed for heavy lats (main kernel skips them).
// ---------------------------------------------------------------------------
__global__ __launch_bounds__(256) void scan_kernel(
    const int* __restrict__ cnt_a, const int* __restrict__ jlo_a,
    int* __restrict__ off_a, int4* __restrict__ rowmeta,
    int4* __restrict__ rowmetaL, int tap_cap)
{
  __shared__ int buf[256];
  __shared__ int carry;
  int tid = threadIdx.x;
  if (tid == 0) carry = 0;
  __syncthreads();
  for (int base = 0; base < NROWS; base += 256) {
    int i = base + tid;
    int v = (i < NROWS) ? ((cnt_a[i] + 3) & ~3) : 0;
    buf[tid] = v;
    __syncthreads();
    for (int s = 1; s < 256; s <<= 1) {
      int t = (tid >= s) ? buf[tid - s] : 0;
      __syncthreads();
      buf[tid] += t;
      __syncthreads();
    }
    if (i < NROWS) off_a[i] = carry + buf[tid] - v;   // exclusive
    __syncthreads();
    if (tid == 255) carry += buf[255];
    __syncthreads();
  }
  __syncthreads();
  for (int r = tid; r < NROWS; r += 256) {
    int off = off_a[r];
    int c4  = (cnt_a[r] + 3) & ~3;
    if (off >= tap_cap)           c4 = 0;
    else if (off + c4 > tap_cap)  c4 = (tap_cap - off) & ~3;
    int l = r / ND, d = r - ND * l;
    int iq = min(max(l + d - 2, 0), NLAT - 1);
    rowmeta[r]  = make_int4(iq * NLON, jlo_a[r], c4, off);
    bool hv = (l < HLO) | (l > NLAT - 1 - HLO);
    rowmetaL[r] = make_int4(iq * NLON, jlo_a[r], hv ? 0 : c4, off);
  }
}

// ---------------------------------------------------------------------------
// Kernel C: fill weight pool (Kg_c, Kg_s, Kd_c, Kd_s), zero-padded to x4.
// ---------------------------------------------------------------------------
__global__ __launch_bounds__(64) void fill_kernel(
    const float* __restrict__ Kgc, const float* __restrict__ Kgs,
    const float* __restrict__ Kdc, const float* __restrict__ Kds,
    const int* __restrict__ jlo_a, const int* __restrict__ cnt_a,
    const int* __restrict__ off_a,
    float4* __restrict__ tapw, int tap_cap)
{
  int row = blockIdx.x;
  int jlo = jlo_a[row], cnt = cnt_a[row], off = off_a[row];
  int cnt4 = (cnt + 3) & ~3;
  for (int t = threadIdx.x; t < cnt4; t += 64) {
    int p = off + t;
    if (p >= tap_cap) break;
    float4 w = make_float4(0.f, 0.f, 0.f, 0.f);
    if (t < cnt) {
      int j = jlo + t;
      int m = j + ((j < 0) ? NLON : 0);
      size_t idx = (size_t)row * NLON + m;
      w = make_float4(Kgc[idx], Kgs[idx], Kdc[idx], Kds[idx]);
    }
    tapw[p] = w;
  }
}

// ---------------------------------------------------------------------------
// accK zero-init (once, before stage 1; stages re-zero in main epilogue)
// ---------------------------------------------------------------------------
__global__ __launch_bounds__(256) void zero_acc(float* __restrict__ accK)
{
  int i = blockIdx.x * 256 + threadIdx.x;
  if (i < ACC_N) accK[i] = 0.f;
}

// ---------------------------------------------------------------------------
// HEAVY conv kernel: polar lats' convolution spread over (lat,b) x 6 col-
// chunks x 48 tap-slices.  Block 256 = 4 waves, wave owns one 32-tap slice
// for 240 cols (lane: 4 cols, rolling register window from global, L1-hot).
// Partials committed via f32 HW atomics into accK[hl][b][f][col].
// ---------------------------------------------------------------------------
__global__ __launch_bounds__(256, 8) void heavy_conv(
    const float* __restrict__ Xh, const float* __restrict__ Xuv,
    const int4* __restrict__ rowmeta, const float4* __restrict__ tapw,
    float* __restrict__ accK)
{
  int yb = blockIdx.y;
  int hl = yb >> 2, b = yb & 3;
  int l  = (hl < HLO) ? hl : (NLAT - NHL + hl);   // 0..11, 709..720
  int cb = blockIdx.x / 12;                       // 0..5
  int q  = blockIdx.x % 12;
  int tid = threadIdx.x;
  int wv = tid >> 6, lane = tid & 63;
  int sl = q * 4 + wv;                            // 0..47

  int4 rms[ND];
  int ns[ND + 1];
  ns[0] = 0;
#pragma unroll
  for (int d = 0; d < ND; ++d) {
    rms[d] = rowmeta[l * ND + d];
    ns[d + 1] = ns[d] + (rms[d].z + HTC - 1) / HTC;
  }
  if (sl >= ns[ND] || lane >= 60) return;

  int4 rm = make_int4(0, 0, 0, 0);
  int tc = 0;
#pragma unroll
  for (int d = 0; d < ND; ++d)
    if (sl >= ns[d] && sl < ns[d + 1]) { rm = rms[d]; tc = (sl - ns[d]) * HTC; }
  int wcnt = min(HTC, rm.z - tc);

  const float* __restrict__ grh  = Xh  + (size_t)b * PLANE + rm.x;
  const float* __restrict__ gruv = Xuv + (size_t)b * PLANE * 2 + 2 * (size_t)rm.x;
  int col = cb * 240 + 4 * lane;
  int m = col + rm.y + tc;
  m %= NLON; if (m < 0) m += NLON;

  int g0 = m, g1 = m + 1, g2 = m + 2, g3 = m + 3;
  if (g1 >= NLON) g1 -= NLON;
  if (g2 >= NLON) g2 -= NLON;
  if (g3 >= NLON) g3 -= NLON;
  float H0 = grh[g0], H1 = grh[g1], H2 = grh[g2], H3 = grh[g3];
  float2 t0 = *(const float2*)(gruv + 2 * g0);
  float2 t1 = *(const float2*)(gruv + 2 * g1);
  float2 t2 = *(const float2*)(gruv + 2 * g2);
  float2 t3 = *(const float2*)(gruv + 2 * g3);
  float U0 = t0.x, U1 = t1.x, U2 = t2.x, U3 = t3.x;
  float V0 = t0.y, V1 = t1.y, V2 = t2.y, V3 = t3.y;

  float ah0 = 0.f, ah1 = 0.f, ah2 = 0.f, ah3 = 0.f;
  float au0 = 0.f, au1 = 0.f, au2 = 0.f, au3 = 0.f;
  float av0 = 0.f, av1 = 0.f, av2 = 0.f, av3 = 0.f;

  int gp = g3;
#pragma unroll 4
  for (int tt = 0; tt < wcnt; ++tt) {
    float4 W = tapw[rm.w + tc + tt];
    ++gp; if (gp == NLON) gp = 0;
    float  hn = grh[gp];
    float2 un = *(const float2*)(gruv + 2 * gp);
    ah0 = fmaf(W.z, U0, ah0); ah0 = fmaf(W.w, V0, ah0);
    au0 = fmaf(W.x, H0, au0); av0 = fmaf(W.y, H0, av0);
    ah1 = fmaf(W.z, U1, ah1); ah1 = fmaf(W.w, V1, ah1);
    au1 = fmaf(W.x, H1, au1); av1 = fmaf(W.y, H1, av1);
    ah2 = fmaf(W.z, U2, ah2); ah2 = fmaf(W.w, V2, ah2);
    au2 = fmaf(W.x, H2, au2); av2 = fmaf(W.y, H2, av2);
    ah3 = fmaf(W.z, U3, ah3); ah3 = fmaf(W.w, V3, ah3);
    au3 = fmaf(W.x, H3, au3); av3 = fmaf(W.y, H3, av3);
    H0 = H1; H1 = H2; H2 = H3; H3 = hn;
    U0 = U1; U1 = U2; U2 = U3; U3 = un.x;
    V0 = V1; V1 = V2; V2 = V3; V3 = un.y;
  }

  float* ap = accK + (size_t)(hl * NB + b) * 3 * NLON + col;
  unsafeAtomicAdd(ap + 0,            ah0);
  unsafeAtomicAdd(ap + 1,            ah1);
  unsafeAtomicAdd(ap + 2,            ah2);
  unsafeAtomicAdd(ap + 3,            ah3);
  unsafeAtomicAdd(ap + NLON + 0,     au0);
  unsafeAtomicAdd(ap + NLON + 1,     au1);
  unsafeAtomicAdd(ap + NLON + 2,     au2);
  unsafeAtomicAdd(ap + NLON + 3,     au3);
  unsafeAtomicAdd(ap + 2*NLON + 0,   av0);
  unsafeAtomicAdd(ap + 2*NLON + 1,   av1);
  unsafeAtomicAdd(ap + 2*NLON + 2,   av2);
  unsafeAtomicAdd(ap + 2*NLON + 3,   av3);
}

// ---------------------------------------------------------------------------
// MAIN stage kernel (round-2 structure, verified @167us/stage; now light lats
// only do taps: rowmetaL has heavy lats zeroed -> nit<=3 < NT -> exactly one
// lockstep iteration).  Heavy lats: skip loop, epilogue pulls k from accK and
// zeroes it for the next stage (same-stream ordering guarantees safety).
// mode 0: O = S0 + cdt*k ; mode 1: O = (X1+2*X2+X3-S0)/3 + (DT/6)*k4
// ---------------------------------------------------------------------------
#define TAP(W, a, b, c, d)                                                   \
  ah0 = fmaf(W.z, U##a, ah0); ah0 = fmaf(W.w, V##a, ah0);                    \
  au0 = fmaf(W.x, H##a, au0); av0 = fmaf(W.y, H##a, av0);                    \
  ah1 = fmaf(W.z, U##b, ah1); ah1 = fmaf(W.w, V##b, ah1);                    \
  au1 = fmaf(W.x, H##b, au1); av1 = fmaf(W.y, H##b, av1);                    \
  ah2 = fmaf(W.z, U##c, ah2); ah2 = fmaf(W.w, V##c, ah2);                    \
  au2 = fmaf(W.x, H##c, au2); av2 = fmaf(W.y, H##c, av2);                    \
  ah3 = fmaf(W.z, U##d, ah3); ah3 = fmaf(W.w, V##d, ah3);                    \
  au3 = fmaf(W.x, H##d, au3); av3 = fmaf(W.y, H##d, av3);

__global__ __launch_bounds__(BT, 4) void stage_kernel(
    const float* __restrict__ Xh,  const float* __restrict__ Xuv,
    const float* __restrict__ S0h, const float* __restrict__ S0uv,
    const float* __restrict__ X1h, const float* __restrict__ X1uv,
    const float* __restrict__ X2h, const float* __restrict__ X2uv,
    const float* __restrict__ fcor,
    const int4* __restrict__ rowmetaL, const float4* __restrict__ tapw,
    float* __restrict__ accK,
    float* __restrict__ Oh, float* __restrict__ Ouv,
    float cdt, int mode)
{
  __shared__ __align__(16) float smem[NT * TEAM_F];

  int y  = blockIdx.y;
  int ly = y >> 2;                   // NB == 4
  int b  = y & 3;
  int l  = (ly & 1) ? (NLAT - 1 - (ly >> 1)) : (ly >> 1);   // heavy-first
  int c0 = blockIdx.x * NCOLS;
  int tid  = threadIdx.x;
  int team = tid / TBT;              // 0..NT-1
  int ttid = tid - team * TBT;       // 0..TBT-1
  bool act = ttid < ACT;
  int w = 4 * ttid;                  // local col base (act threads)

  float* __restrict__ sl = smem + team * TEAM_F;
  float* __restrict__ sh = sl;
  float* __restrict__ su = sl + SH_SZ;
  float* __restrict__ sv = sl + 2 * SH_SZ;
  float4* __restrict__ swt = (float4*)(sl + 3 * SH_SZ);

  const float* __restrict__ xh  = Xh  + (size_t)b * PLANE;
  const float* __restrict__ xuv = Xuv + (size_t)b * PLANE * 2;

  // --- uniform per-lat work-item partition: item -> (d row, tap chunk) ---
  int4 rms[ND];
  int ns[ND + 1];
  ns[0] = 0;
#pragma unroll
  for (int d = 0; d < ND; ++d) {
    rms[d] = rowmetaL[l * ND + d];
    ns[d + 1] = ns[d] + (rms[d].z + TCH - 1) / TCH;
  }
  int nit = ns[ND];

  float ah0 = 0.f, ah1 = 0.f, ah2 = 0.f, ah3 = 0.f;
  float au0 = 0.f, au1 = 0.f, au2 = 0.f, au3 = 0.f;
  float av0 = 0.f, av1 = 0.f, av2 = 0.f, av3 = 0.f;

  for (int it0 = 0; it0 < nit; it0 += NT) {
    int item = it0 + team;
    int tc = -1;
    int4 rm = make_int4(0, 0, 0, 0);
#pragma unroll
    for (int d = 0; d < ND; ++d)
      if (item >= ns[d] && item < ns[d + 1]) { rm = rms[d]; tc = (item - ns[d]) * TCH; }

    __syncthreads();                        // prior iteration's readers done
    int wcnt = 0;
    if (tc >= 0) {
      wcnt = min(TCH, rm.z - tc);           // multiple of 4
      int wlen = NCOLS - 1 + wcnt + 3;      // indices 0 .. 722+wcnt
      int gg = c0 + rm.y + tc;              // window start, unwrapped
      gg %= NLON; gg += (gg < 0) ? NLON : 0;
      const float* __restrict__ grh  = xh  + rm.x;
      const float* __restrict__ gruv = xuv + 2 * (size_t)rm.x;
      for (int e = ttid; e < wlen; e += TBT) {
        int g = gg + e;                     // < 1440 + 984
        g -= (g >= NLON) ? NLON : 0;
        float  hh = grh[g];
        float2 uv = *(const float2*)(gruv + 2 * g);
        sh[e] = hh; su[e] = uv.x; sv[e] = uv.y;
      }
      for (int k = ttid; k < wcnt; k += TBT) swt[k] = tapw[rm.w + tc + k];
    }
    __syncthreads();                        // all teams staged

    if (tc >= 0 && act) {
      const float4* __restrict__ ph = (const float4*)(sh + w);  // 16B aligned
      const float4* __restrict__ pu = (const float4*)(su + w);
      const float4* __restrict__ pv = (const float4*)(sv + w);
      float4 Ha = ph[0], Ua = pu[0], Va = pv[0];
      for (int tg = 0; tg < wcnt; tg += 4) {
        int q = (tg >> 2) + 1;
        float4 W0 = swt[tg], W1 = swt[tg + 1], W2 = swt[tg + 2], W3 = swt[tg + 3];
        float4 Hb = ph[q], Ub = pu[q], Vb = pv[q];
        float H0 = Ha.x, H1 = Ha.y, H2 = Ha.z, H3 = Ha.w;
        float H4 = Hb.x, H5 = Hb.y, H6 = Hb.z;
        float U0 = Ua.x, U1 = Ua.y, U2 = Ua.z, U3 = Ua.w;
        float U4 = Ub.x, U5 = Ub.y, U6 = Ub.z;
        float V0 = Va.x, V1 = Va.y, V2 = Va.z, V3 = Va.w;
        float V4 = Vb.x, V5 = Vb.y, V6 = Vb.z;
        TAP(W0, 0, 1, 2, 3)
        TAP(W1, 1, 2, 3, 4)
        TAP(W2, 2, 3, 4, 5)
        TAP(W3, 3, 4, 5, 6)
        Ha = Hb; Ua = Ub; Va = Vb;
      }
    }
  }

  // ---- cross-team combine: teams 1..3 dump partials into own slice ----
  __syncthreads();                          // all compute reads of LDS done
  if (team != 0 && act) {
    *(float4*)(sh + w) = make_float4(ah0, ah1, ah2, ah3);
    *(float4*)(su + w) = make_float4(au0, au1, au2, au3);
    *(float4*)(sv + w) = make_float4(av0, av1, av2, av3);
  }
  __syncthreads();

  // ---- epilogue (team 0): combine or read accK; Coriolis + RK4 ----
  if (team == 0 && act) {
    if (is_heavy(l)) {
      int hl = (l < HLO) ? l : (l - (NLAT - NHL));
      float* ap = accK + (size_t)(hl * NB + b) * 3 * NLON + c0 + w;
      float4 A = *(const float4*)(ap);
      float4 B = *(const float4*)(ap + NLON);
      float4 C = *(const float4*)(ap + 2 * NLON);
      ah0 = A.x; ah1 = A.y; ah2 = A.z; ah3 = A.w;
      au0 = B.x; au1 = B.y; au2 = B.z; au3 = B.w;
      av0 = C.x; av1 = C.y; av2 = C.z; av3 = C.w;
      float4 z = make_float4(0.f, 0.f, 0.f, 0.f);
      *(float4*)(ap)            = z;       // re-zero for next stage
      *(float4*)(ap + NLON)     = z;
      *(float4*)(ap + 2 * NLON) = z;
    } else {
#pragma unroll
      for (int t = 1; t < NT; ++t) {
        const float* __restrict__ s2 = smem + t * TEAM_F;
        float4 A = *(const float4*)(s2 + w);
        float4 B = *(const float4*)(s2 + SH_SZ + w);
        float4 C = *(const float4*)(s2 + 2 * SH_SZ + w);
        ah0 += A.x; ah1 += A.y; ah2 += A.z; ah3 += A.w;
        au0 += B.x; au1 += B.y; au2 += B.z; au3 += B.w;
        av0 += C.x; av1 += C.y; av2 += C.z; av3 += C.w;
      }
    }

    size_t ih  = (size_t)b * PLANE + (size_t)l * NLON + c0 + w;
    size_t iuv = 2 * ih;
    float f = fcor[l];
    float4 xa = *(const float4*)(Xuv + iuv);      // u0,v0,u1,v1
    float4 xb = *(const float4*)(Xuv + iuv + 4);  // u2,v2,u3,v3
    float kh0 = -ah0, kh1 = -ah1, kh2 = -ah2, kh3 = -ah3;
    float ku0 = fmaf(-f, xa.y, -au0), kv0 = fmaf(f, xa.x, -av0);
    float ku1 = fmaf(-f, xa.w, -au1), kv1 = fmaf(f, xa.z, -av1);
    float ku2 = fmaf(-f, xb.y, -au2), kv2 = fmaf(f, xb.x, -av2);
    float ku3 = fmaf(-f, xb.w, -au3), kv3 = fmaf(f, xb.z, -av3);

    if (mode == 0) {
      float4 s0 = *(const float4*)(S0h + ih);
      *(float4*)(Oh + ih) = make_float4(fmaf(cdt, kh0, s0.x), fmaf(cdt, kh1, s0.y),
                                        fmaf(cdt, kh2, s0.z), fmaf(cdt, kh3, s0.w));
      float4 sa = *(const float4*)(S0uv + iuv);
      float4 sb = *(const float4*)(S0uv + iuv + 4);
      *(float4*)(Ouv + iuv)     = make_float4(fmaf(cdt, ku0, sa.x), fmaf(cdt, kv0, sa.y),
                                              fmaf(cdt, ku1, sa.z), fmaf(cdt, kv1, sa.w));
      *(float4*)(Ouv + iuv + 4) = make_float4(fmaf(cdt, ku2, sb.x), fmaf(cdt, kv2, sb.y),
                                              fmaf(cdt, ku3, sb.z), fmaf(cdt, kv3, sb.w));
    } else {
      const float DT6 = DTSTEP / 6.0f;
      const float TH  = 1.0f / 3.0f;
      float4 xh3 = *(const float4*)(Xh + ih);   // X3 h at own cols
      float4 s0 = *(const float4*)(S0h + ih);
      float4 x1 = *(const float4*)(X1h + ih);
      float4 x2 = *(const float4*)(X2h + ih);
      *(float4*)(Oh + ih) = make_float4(
        TH * (x1.x + 2.f * x2.x + xh3.x - s0.x) + DT6 * kh0,
        TH * (x1.y + 2.f * x2.y + xh3.y - s0.y) + DT6 * kh1,
        TH * (x1.z + 2.f * x2.z + xh3.z - s0.z) + DT6 * kh2,
        TH * (x1.w + 2.f * x2.w + xh3.w - s0.w) + DT6 * kh3);
      float4 sa = *(const float4*)(S0uv + iuv);
      float4 sb = *(const float4*)(S0uv + iuv + 4);
      float4 xa1 = *(const float4*)(X1uv + iuv);
      float4 xb1 = *(const float4*)(X1uv + iuv + 4);
      float4 xa2 = *(const float4*)(X2uv + iuv);
      float4 xb2 = *(const float4*)(X2uv + iuv + 4);
      *(float4*)(Ouv + iuv) = make_float4(
        TH * (xa1.x + 2.f * xa2.x + xa.x - sa.x) + DT6 * ku0,
        TH * (xa1.y + 2.f * xa2.y + xa.y - sa.y) + DT6 * kv0,
        TH * (xa1.z + 2.f * xa2.z + xa.z - sa.z) + DT6 * ku1,
        TH * (xa1.w + 2.f * xa2.w + xa.w - sa.w) + DT6 * kv1);
      *(float4*)(Ouv + iuv + 4) = make_float4(
        TH * (xb1.x + 2.f * xb2.x + xb.x - sb.x) + DT6 * ku2,
        TH * (xb1.y + 2.f * xb2.y + xb.y - sb.y) + DT6 * kv2,
        TH * (xb1.z + 2.f * xb2.z + xb.z - sb.z) + DT6 * ku3,
        TH * (xb1.w + 2.f * xb2.w + xb.w - sb.w) + DT6 * kv3);
    }
  }
}

// ---------------------------------------------------------------------------
extern "C" void kernel_launch(void* const* d_in, const int* in_sizes, int n_in,
                              void* d_out, int out_size, void* d_ws, size_t ws_size,
                              hipStream_t stream)
{
  const float* h0   = (const float*)d_in[0];
  const float* uv0  = (const float*)d_in[1];
  const float* Kgc  = (const float*)d_in[2];
  const float* Kgs  = (const float*)d_in[3];
  const float* Kdc  = (const float*)d_in[4];
  const float* Kds  = (const float*)d_in[5];
  const float* fcor = (const float*)d_in[6];

  char* ws = (char*)d_ws;
  size_t pos = 0;
  auto carve = [&](size_t bytes) -> void* {
    void* p = ws + pos;
    pos += (bytes + 255) & ~(size_t)255;
    return p;
  };

  int*   jlo_a    = (int*)carve(sizeof(int) * NROWS);
  int*   cnt_a    = (int*)carve(sizeof(int) * NROWS);
  int*   off_a    = (int*)carve(sizeof(int) * NROWS);
  int4*  rowmeta  = (int4*)carve(sizeof(int4) * NROWS);
  int4*  rowmetaL = (int4*)carve(sizeof(int4) * NROWS);
  float* accK     = (float*)carve(sizeof(float) * ACC_N);
  float* X1       = (float*)carve(sizeof(float) * 3 * (size_t)HVOL);
  float* X2       = (float*)carve(sizeof(float) * 3 * (size_t)HVOL);
  float* X3       = (float*)carve(sizeof(float) * 3 * (size_t)HVOL);
  float4* tapw    = (float4*)carve(sizeof(float4) * (size_t)TAPCAP);

  float* X1h = X1;  float* X1uv = X1 + HVOL;
  float* X2h = X2;  float* X2uv = X2 + HVOL;
  float* X3h = X3;  float* X3uv = X3 + HVOL;
  float* out_h  = (float*)d_out;          // [NB,1,NLAT,NLON]
  float* out_uv = (float*)d_out + HVOL;   // [NB,1,NLAT,NLON,2]

  support_kernel<<<NROWS, 64, 0, stream>>>(Kgc, Kgs, Kdc, Kds, jlo_a, cnt_a);
  scan_kernel<<<1, 256, 0, stream>>>(cnt_a, jlo_a, off_a, rowmeta, rowmetaL, TAPCAP);
  fill_kernel<<<NROWS, 64, 0, stream>>>(Kgc, Kgs, Kdc, Kds, jlo_a, cnt_a, off_a,
                                        tapw, TAPCAP);
  zero_acc<<<(ACC_N + 255) / 256, 256, 0, stream>>>(accK);

  dim3 gs(2, NLAT * NB);
  dim3 gh(72, NHL * NB);

  // stage 1: k1 from S0; X1 = S0 + dt/2 k1
  heavy_conv<<<gh, 256, 0, stream>>>(h0, uv0, rowmeta, tapw, accK);
  stage_kernel<<<gs, BT, 0, stream>>>(h0, uv0, h0, uv0, h0, uv0, h0, uv0, fcor,
                                      rowmetaL, tapw, accK, X1h, X1uv, 0.5f * DTSTEP, 0);
  // stage 2: k2 from X1; X2 = S0 + dt/2 k2
  heavy_conv<<<gh, 256, 0, stream>>>(X1h, X1uv, rowmeta, tapw, accK);
  stage_kernel<<<gs, BT, 0, stream>>>(X1h, X1uv, h0, uv0, h0, uv0, h0, uv0, fcor,
                                      rowmetaL, tapw, accK, X2h, X2uv, 0.5f * DTSTEP, 0);
  // stage 3: k3 from X2; X3 = S0 + dt k3
  heavy_conv<<<gh, 256, 0, stream>>>(X2h, X2uv, rowmeta, tapw, accK);
  stage_kernel<<<gs, BT, 0, stream>>>(X2h, X2uv, h0, uv0, h0, uv0, h0, uv0, fcor,
                                      rowmetaL, tapw, accK, X3h, X3uv, DTSTEP, 0);
  // stage 4: k4 from X3; out = (X1 + 2 X2 + X3 - S0)/3 + dt/6 k4
  heavy_conv<<<gh, 256, 0, stream>>>(X3h, X3uv, rowmeta, tapw, accK);
  stage_kernel<<<gs, BT, 0, stream>>>(X3h, X3uv, h0, uv0, X1h, X1uv, X2h, X2uv, fcor,
                                      rowmetaL, tapw, accK, out_h, out_uv, 0.0f, 1);
}

// Round 8
// 872.820 us; speedup vs baseline: 1.3854x; 1.3854x over previous
//
#include <hip/hip_runtime.h>

#define NLAT 721
#define NLON 1440
#define NB 4
#define ND 5
#define NROWS (NLAT*ND)          // 3605
#define PLANE (NLAT*NLON)        // 1,038,240
#define HVOL (NB*PLANE)          // 4,152,960
#define DTSTEP 0.01f
#define TAPCAP 262144

// ---- light kernel geometry (lats 4..716) ----
#define LBT 192                  // 3 waves
#define LACT 180                 // act threads x 4 cols = 720
#define LNC 720                  // cols per block
#define LTC 240                  // taps per chunk (light rows: cnt <= ~232 -> 1 chunk)
#define LW  992                  // window floats per field (962 + swizzle margin)

// ---- heavy kernel geometry (lats 0..3, 717..720) ----
#define NHL 8
#define HBT 512                  // 8 waves
#define HNW 8
#define HNC 240                  // cols per tile (6 tiles)
#define HCHK 64                  // taps per wave-chunk
#define HW 1712                  // window floats per field (1682 + swizzle margin)
#define HSM 5760                 // block smem floats (3*HW=5136 window; 8*720 combine)

// ---------------------------------------------------------------------------
// Kernel A: per (lat,d) row, find the wrapped-interval support [jlo, jhi]
// ---------------------------------------------------------------------------
__global__ __launch_bounds__(64) void support_kernel(
    const float* __restrict__ Kgc, const float* __restrict__ Kgs,
    const float* __restrict__ Kdc, const float* __restrict__ Kds,
    int* __restrict__ jlo_a, int* __restrict__ cnt_a)
{
  int row = blockIdx.x;
  int lane = threadIdx.x;
  const float* a = Kgc + (size_t)row * NLON;
  const float* b = Kgs + (size_t)row * NLON;
  const float* c = Kdc + (size_t)row * NLON;
  const float* d = Kds + (size_t)row * NLON;
  int jmin = 1 << 30, jmax = -(1 << 30);
  for (int m = lane; m < NLON; m += 64) {
    float s = fabsf(a[m]) + fabsf(b[m]) + fabsf(c[m]) + fabsf(d[m]);
    if (s != 0.0f) {
      int j = (m >= NLON / 2) ? (m - NLON) : m;
      jmin = min(jmin, j);
      jmax = max(jmax, j);
    }
  }
  for (int s = 32; s > 0; s >>= 1) {
    jmin = min(jmin, __shfl_down(jmin, s));
    jmax = max(jmax, __shfl_down(jmax, s));
  }
  if (lane == 0) {
    if (jmax < jmin) { jlo_a[row] = 0; cnt_a[row] = 0; }
    else             { jlo_a[row] = jmin; cnt_a[row] = jmax - jmin + 1; }
  }
}

// ---------------------------------------------------------------------------
// Kernel B: prefix sum over 4-padded row counts; per-row meta
// int4(iq*NLON, jlo (signed), cnt4, pool offset).
// ---------------------------------------------------------------------------
__global__ __launch_bounds__(256) void scan_kernel(
    const int* __restrict__ cnt_a, const int* __restrict__ jlo_a,
    int* __restrict__ off_a, int4* __restrict__ rowmeta, int tap_cap)
{
  __shared__ int buf[256];
  __shared__ int carry;
  int tid = threadIdx.x;
  if (tid == 0) carry = 0;
  __syncthreads();
  for (int base = 0; base < NROWS; base += 256) {
    int i = base + tid;
    int v = (i < NROWS) ? ((cnt_a[i] + 3) & ~3) : 0;
    buf[tid] = v;
    __syncthreads();
    for (int s = 1; s < 256; s <<= 1) {
      int t = (tid >= s) ? buf[tid - s] : 0;
      __syncthreads();
      buf[tid] += t;
      __syncthreads();
    }
    if (i < NROWS) off_a[i] = carry + buf[tid] - v;   // exclusive
    __syncthreads();
    if (tid == 255) carry += buf[255];
    __syncthreads();
  }
  __syncthreads();
  for (int r = tid; r < NROWS; r += 256) {
    int off = off_a[r];
    int c4  = (cnt_a[r] + 3) & ~3;
    if (off >= tap_cap)           c4 = 0;
    else if (off + c4 > tap_cap)  c4 = (tap_cap - off) & ~3;
    int l = r / ND, d = r - ND * l;
    int iq = min(max(l + d - 2, 0), NLAT - 1);
    rowmeta[r] = make_int4(iq * NLON, jlo_a[r], c4, off);
  }
}

// ---------------------------------------------------------------------------
// Kernel C: fill weight pool (Kg_c, Kg_s, Kd_c, Kd_s), zero-padded to x4.
// ---------------------------------------------------------------------------
__global__ __launch_bounds__(64) void fill_kernel(
    const float* __restrict__ Kgc, const float* __restrict__ Kgs,
    const float* __restrict__ Kdc, const float* __restrict__ Kds,
    const int* __restrict__ jlo_a, const int* __restrict__ cnt_a,
    const int* __restrict__ off_a,
    float4* __restrict__ tapw, int tap_cap)
{
  int row = blockIdx.x;
  int jlo = jlo_a[row], cnt = cnt_a[row], off = off_a[row];
  int cnt4 = (cnt + 3) & ~3;
  for (int t = threadIdx.x; t < cnt4; t += 64) {
    int p = off + t;
    if (p >= tap_cap) break;
    float4 w = make_float4(0.f, 0.f, 0.f, 0.f);
    if (t < cnt) {
      int j = jlo + t;
      int m = j + ((j < 0) ? NLON : 0);
      size_t idx = (size_t)row * NLON + m;
      w = make_float4(Kgc[idx], Kgs[idx], Kdc[idx], Kds[idx]);
    }
    tapw[p] = w;
  }
}

// ---------------------------------------------------------------------------
// Shared epilogue: Coriolis + RK4 combine for 4 consecutive columns at ih.
// mode 0: O = S0 + cdt*k ; mode 1: O = (X1+2*X2+X3-S0)/3 + (DT/6)*k4
// ---------------------------------------------------------------------------
__device__ __forceinline__ void rk4_epilogue(
    float ah0, float ah1, float ah2, float ah3,
    float au0, float au1, float au2, float au3,
    float av0, float av1, float av2, float av3,
    size_t ih, float f,
    const float* __restrict__ Xh,  const float* __restrict__ Xuv,
    const float* __restrict__ S0h, const float* __restrict__ S0uv,
    const float* __restrict__ X1h, const float* __restrict__ X1uv,
    const float* __restrict__ X2h, const float* __restrict__ X2uv,
    float* __restrict__ Oh, float* __restrict__ Ouv,
    float cdt, int mode)
{
  size_t iuv = 2 * ih;
  float4 xa = *(const float4*)(Xuv + iuv);      // u0,v0,u1,v1
  float4 xb = *(const float4*)(Xuv + iuv + 4);  // u2,v2,u3,v3
  float kh0 = -ah0, kh1 = -ah1, kh2 = -ah2, kh3 = -ah3;
  float ku0 = fmaf(-f, xa.y, -au0), kv0 = fmaf(f, xa.x, -av0);
  float ku1 = fmaf(-f, xa.w, -au1), kv1 = fmaf(f, xa.z, -av1);
  float ku2 = fmaf(-f, xb.y, -au2), kv2 = fmaf(f, xb.x, -av2);
  float ku3 = fmaf(-f, xb.w, -au3), kv3 = fmaf(f, xb.z, -av3);

  if (mode == 0) {
    float4 s0 = *(const float4*)(S0h + ih);
    *(float4*)(Oh + ih) = make_float4(fmaf(cdt, kh0, s0.x), fmaf(cdt, kh1, s0.y),
                                      fmaf(cdt, kh2, s0.z), fmaf(cdt, kh3, s0.w));
    float4 sa = *(const float4*)(S0uv + iuv);
    float4 sb = *(const float4*)(S0uv + iuv + 4);
    *(float4*)(Ouv + iuv)     = make_float4(fmaf(cdt, ku0, sa.x), fmaf(cdt, kv0, sa.y),
                                            fmaf(cdt, ku1, sa.z), fmaf(cdt, kv1, sa.w));
    *(float4*)(Ouv + iuv + 4) = make_float4(fmaf(cdt, ku2, sb.x), fmaf(cdt, kv2, sb.y),
                                            fmaf(cdt, ku3, sb.z), fmaf(cdt, kv3, sb.w));
  } else {
    const float DT6 = DTSTEP / 6.0f;
    const float TH  = 1.0f / 3.0f;
    float4 xh3 = *(const float4*)(Xh + ih);   // X3 h at own cols
    float4 s0 = *(const float4*)(S0h + ih);
    float4 x1 = *(const float4*)(X1h + ih);
    float4 x2 = *(const float4*)(X2h + ih);
    *(float4*)(Oh + ih) = make_float4(
      TH * (x1.x + 2.f * x2.x + xh3.x - s0.x) + DT6 * kh0,
      TH * (x1.y + 2.f * x2.y + xh3.y - s0.y) + DT6 * kh1,
      TH * (x1.z + 2.f * x2.z + xh3.z - s0.z) + DT6 * kh2,
      TH * (x1.w + 2.f * x2.w + xh3.w - s0.w) + DT6 * kh3);
    float4 sa = *(const float4*)(S0uv + iuv);
    float4 sb = *(const float4*)(S0uv + iuv + 4);
    float4 xa1 = *(const float4*)(X1uv + iuv);
    float4 xb1 = *(const float4*)(X1uv + iuv + 4);
    float4 xa2 = *(const float4*)(X2uv + iuv);
    float4 xb2 = *(const float4*)(X2uv + iuv + 4);
    *(float4*)(Ouv + iuv) = make_float4(
      TH * (xa1.x + 2.f * xa2.x + xa.x - sa.x) + DT6 * ku0,
      TH * (xa1.y + 2.f * xa2.y + xa.y - sa.y) + DT6 * kv0,
      TH * (xa1.z + 2.f * xa2.z + xa.z - sa.z) + DT6 * ku1,
      TH * (xa1.w + 2.f * xa2.w + xa.w - sa.w) + DT6 * kv1);
    *(float4*)(Ouv + iuv + 4) = make_float4(
      TH * (xb1.x + 2.f * xb2.x + xb.x - sb.x) + DT6 * ku2,
      TH * (xb1.y + 2.f * xb2.y + xb.y - sb.y) + DT6 * kv2,
      TH * (xb1.z + 2.f * xb2.z + xb.z - sb.z) + DT6 * ku3,
      TH * (xb1.w + 2.f * xb2.w + xb.w - sb.w) + DT6 * kv3);
  }
}

// 16B-block XOR swizzle (verified rounds 4/6): dword-index bits[4:2] ^= bits[8:6];
// preserves float4 contiguity, spreads stride-16B lane patterns across banks.
__device__ __forceinline__ int swz(int d) { return d ^ ((d >> 4) & 28); }
__device__ __forceinline__ float4 ldswz(const float* base, int o) {
  return *(const float4*)(base + swz(o));
}

// 16 FMAs for one tap (weights W), elements a..d per column 0..3
#define TAP(W, a, b, c, d)                                                   \
  ah0 = fmaf(W.z, U##a, ah0); ah0 = fmaf(W.w, V##a, ah0);                    \
  au0 = fmaf(W.x, H##a, au0); av0 = fmaf(W.y, H##a, av0);                    \
  ah1 = fmaf(W.z, U##b, ah1); ah1 = fmaf(W.w, V##b, ah1);                    \
  au1 = fmaf(W.x, H##b, au1); av1 = fmaf(W.y, H##b, av1);                    \
  ah2 = fmaf(W.z, U##c, ah2); ah2 = fmaf(W.w, V##c, ah2);                    \
  au2 = fmaf(W.x, H##c, au2); av2 = fmaf(W.y, H##c, av2);                    \
  ah3 = fmaf(W.z, U##d, ah3); ah3 = fmaf(W.w, V##d, ah3);                    \
  au3 = fmaf(W.x, H##d, au3); av3 = fmaf(W.y, H##d, av3);

// body of one 4-tap group given window float4s Ha..,Hb.. and weights W0..W3
#define GROUP4()                                                             \
  {                                                                          \
    float H0 = Ha.x, H1 = Ha.y, H2 = Ha.z, H3 = Ha.w;                        \
    float H4 = Hb.x, H5 = Hb.y, H6 = Hb.z;                                   \
    float U0 = Ua.x, U1 = Ua.y, U2 = Ua.z, U3 = Ua.w;                        \
    float U4 = Ub.x, U5 = Ub.y, U6 = Ub.z;                                   \
    float V0 = Va.x, V1 = Va.y, V2 = Va.z, V3 = Va.w;                        \
    float V4 = Vb.x, V5 = Vb.y, V6 = Vb.z;                                   \
    TAP(W0, 0, 1, 2, 3)                                                      \
    TAP(W1, 1, 2, 3, 4)                                                      \
    TAP(W2, 2, 3, 4, 5)                                                      \
    TAP(W3, 3, 4, 5, 6)                                                      \
    Ha = Hb; Ua = Ub; Va = Vb;                                               \
  }

// ---------------------------------------------------------------------------
// LIGHT kernel (lats 4..716; support <= ~232/row, rows d=1..3 active).
// Block 192 (3 waves), 12 KB LDS -> 10 blocks/CU (30 waves).  Per active row:
// stage swizzled window once, one barrier, rolling-float4 tap loop; weights
// straight from global (uniform address via readfirstlane).  Chunk loop kept
// for correctness at any cnt.
// ---------------------------------------------------------------------------
__global__ __launch_bounds__(LBT, 8) void light_kernel(
    const float* __restrict__ Xh,  const float* __restrict__ Xuv,
    const float* __restrict__ S0h, const float* __restrict__ S0uv,
    const float* __restrict__ X1h, const float* __restrict__ X1uv,
    const float* __restrict__ X2h, const float* __restrict__ X2uv,
    const float* __restrict__ fcor,
    const int4* __restrict__ rowmeta, const float4* __restrict__ tapw,
    float* __restrict__ Oh, float* __restrict__ Ouv,
    float cdt, int mode)
{
  __shared__ __align__(16) float smem[3 * LW];
  float* __restrict__ sh = smem;
  float* __restrict__ su = smem + LW;
  float* __restrict__ sv = smem + 2 * LW;

  int y  = blockIdx.y;
  int b  = y & 3;
  int l  = 4 + (y >> 2);             // 4..716
  int c0 = blockIdx.x * LNC;
  int tid = threadIdx.x;
  bool act = tid < LACT;
  int w = 4 * tid;

  const float* __restrict__ xh  = Xh  + (size_t)b * PLANE;
  const float* __restrict__ xuv = Xuv + (size_t)b * PLANE * 2;

  float ah0 = 0.f, ah1 = 0.f, ah2 = 0.f, ah3 = 0.f;
  float au0 = 0.f, au1 = 0.f, au2 = 0.f, au3 = 0.f;
  float av0 = 0.f, av1 = 0.f, av2 = 0.f, av3 = 0.f;

  for (int d = 0; d < ND; ++d) {
    int4 rm = rowmeta[l * ND + d];   // uniform
    int cnt = rm.z;
    if (cnt == 0) continue;
    const float* __restrict__ grh  = xh  + rm.x;
    const float* __restrict__ gruv = xuv + 2 * (size_t)rm.x;

    for (int tc = 0; tc < cnt; tc += LTC) {
      int wcnt = min(LTC, cnt - tc);           // multiple of 4
      int wlen = LNC - 1 + wcnt + 3;           // <= 962
      int gg = c0 + rm.y + tc;
      gg %= NLON; if (gg < 0) gg += NLON;

      __syncthreads();                         // prior chunk's readers done
      for (int e = tid; e < wlen; e += LBT) {
        int g = gg + e;                        // < 1440 + 962
        g -= (g >= NLON) ? NLON : 0;
        float  hh = grh[g];
        float2 uv = *(const float2*)(gruv + 2 * g);
        int se = swz(e);
        sh[se] = hh; su[se] = uv.x; sv[se] = uv.y;
      }
      __syncthreads();

      if (act) {
        int wb = __builtin_amdgcn_readfirstlane(rm.w + tc);
        float4 Ha = ldswz(sh, w), Ua = ldswz(su, w), Va = ldswz(sv, w);
        for (int tg = 0; tg < wcnt; tg += 4) {
          float4 W0 = tapw[wb + tg],     W1 = tapw[wb + tg + 1];
          float4 W2 = tapw[wb + tg + 2], W3 = tapw[wb + tg + 3];
          float4 Hb = ldswz(sh, w + tg + 4);
          float4 Ub = ldswz(su, w + tg + 4);
          float4 Vb = ldswz(sv, w + tg + 4);
          GROUP4()
        }
      }
    }
  }

  if (act) {
    size_t ih = (size_t)b * PLANE + (size_t)l * NLON + c0 + w;
    rk4_epilogue(ah0, ah1, ah2, ah3, au0, au1, au2, au3, av0, av1, av2, av3,
                 ih, fcor[l], Xh, Xuv, S0h, S0uv, X1h, X1uv, X2h, X2uv,
                 Oh, Ouv, cdt, mode);
  }
}

// ---------------------------------------------------------------------------
// HEAVY kernel (lats 0..3, 717..720).  Grid (6 tiles, 32 pairs).  Block 512 =
// 8 waves; per active row: stage full swizzled window once (shared), then the
// 8 waves stride 64-tap chunks of the row (register partials, no atomics).
// Final LDS combine (reuses window buffer) + direct RK4 epilogue.
// ---------------------------------------------------------------------------
__global__ __launch_bounds__(HBT, 8) void heavy_kernel(
    const float* __restrict__ Xh,  const float* __restrict__ Xuv,
    const float* __restrict__ S0h, const float* __restrict__ S0uv,
    const float* __restrict__ X1h, const float* __restrict__ X1uv,
    const float* __restrict__ X2h, const float* __restrict__ X2uv,
    const float* __restrict__ fcor,
    const int4* __restrict__ rowmeta, const float4* __restrict__ tapw,
    float* __restrict__ Oh, float* __restrict__ Ouv,
    float cdt, int mode)
{
  __shared__ __align__(16) float smem[HSM];
  float* __restrict__ sh = smem;
  float* __restrict__ su = smem + HW;
  float* __restrict__ sv = smem + 2 * HW;

  int yb = blockIdx.y;
  int lh = yb >> 2, b = yb & 3;
  int l  = (lh < 4) ? lh : (713 + lh);        // 0..3, 717..720
  int c0 = blockIdx.x * HNC;
  int tid = threadIdx.x;
  int wv = tid >> 6, lane = tid & 63;
  bool act = lane < 60;
  int w = 4 * lane;                           // 0..236 (act)

  const float* __restrict__ xh  = Xh  + (size_t)b * PLANE;
  const float* __restrict__ xuv = Xuv + (size_t)b * PLANE * 2;

  float ah0 = 0.f, ah1 = 0.f, ah2 = 0.f, ah3 = 0.f;
  float au0 = 0.f, au1 = 0.f, au2 = 0.f, au3 = 0.f;
  float av0 = 0.f, av1 = 0.f, av2 = 0.f, av3 = 0.f;

  for (int d = 0; d < ND; ++d) {
    int4 rm = rowmeta[l * ND + d];            // uniform
    int cnt = rm.z;
    if (cnt == 0) continue;
    const float* __restrict__ grh  = xh  + rm.x;
    const float* __restrict__ gruv = xuv + 2 * (size_t)rm.x;

    int wlen = HNC - 1 + cnt + 3;             // <= 1682
    int gg = c0 + rm.y;
    gg %= NLON; if (gg < 0) gg += NLON;

    __syncthreads();                          // prior row's readers done
    for (int e = tid; e < wlen; e += HBT) {
      int g = gg + e;                         // < 1440 + 1682
      g -= (g >= NLON) ? NLON : 0;
      g -= (g >= NLON) ? NLON : 0;
      float  hh = grh[g];
      float2 uv = *(const float2*)(gruv + 2 * g);
      int se = swz(e);
      sh[se] = hh; su[se] = uv.x; sv[se] = uv.y;
    }
    __syncthreads();                          // window staged

    if (act) {
      int nch = (cnt + HCHK - 1) / HCHK;
      for (int cc = wv; cc < nch; cc += HNW) {
        int tb = cc * HCHK;
        int twcnt = min(HCHK, cnt - tb);      // multiple of 4
        int wb = __builtin_amdgcn_readfirstlane(rm.w + tb);
        int o0 = w + tb;
        float4 Ha = ldswz(sh, o0), Ua = ldswz(su, o0), Va = ldswz(sv, o0);
        for (int tg = 0; tg < twcnt; tg += 4) {
          float4 W0 = tapw[wb + tg],     W1 = tapw[wb + tg + 1];
          float4 W2 = tapw[wb + tg + 2], W3 = tapw[wb + tg + 3];
          float4 Hb = ldswz(sh, o0 + tg + 4);
          float4 Ub = ldswz(su, o0 + tg + 4);
          float4 Vb = ldswz(sv, o0 + tg + 4);
          GROUP4()
        }
      }
    }
  }

  // ---- cross-wave combine (reuse smem; all compute reads done) ----
  __syncthreads();
  if (act) {
    float* cs = smem + wv * 720;
    *(float4*)(cs + w)        = make_float4(ah0, ah1, ah2, ah3);
    *(float4*)(cs + 240 + w)  = make_float4(au0, au1, au2, au3);
    *(float4*)(cs + 480 + w)  = make_float4(av0, av1, av2, av3);
  }
  __syncthreads();

  if (tid < 60) {
    int c4 = 4 * tid;
    float h0 = 0.f, h1 = 0.f, h2 = 0.f, h3 = 0.f;
    float u0 = 0.f, u1 = 0.f, u2 = 0.f, u3 = 0.f;
    float v0 = 0.f, v1 = 0.f, v2 = 0.f, v3 = 0.f;
#pragma unroll
    for (int t = 0; t < HNW; ++t) {
      const float* cs = smem + t * 720;
      float4 A = *(const float4*)(cs + c4);
      float4 B = *(const float4*)(cs + 240 + c4);
      float4 C = *(const float4*)(cs + 480 + c4);
      h0 += A.x; h1 += A.y; h2 += A.z; h3 += A.w;
      u0 += B.x; u1 += B.y; u2 += B.z; u3 += B.w;
      v0 += C.x; v1 += C.y; v2 += C.z; v3 += C.w;
    }
    size_t ih = (size_t)b * PLANE + (size_t)l * NLON + c0 + c4;
    rk4_epilogue(h0, h1, h2, h3, u0, u1, u2, u3, v0, v1, v2, v3,
                 ih, fcor[l], Xh, Xuv, S0h, S0uv, X1h, X1uv, X2h, X2uv,
                 Oh, Ouv, cdt, mode);
  }
}

// ---------------------------------------------------------------------------
extern "C" void kernel_launch(void* const* d_in, const int* in_sizes, int n_in,
                              void* d_out, int out_size, void* d_ws, size_t ws_size,
                              hipStream_t stream)
{
  const float* h0   = (const float*)d_in[0];
  const float* uv0  = (const float*)d_in[1];
  const float* Kgc  = (const float*)d_in[2];
  const float* Kgs  = (const float*)d_in[3];
  const float* Kdc  = (const float*)d_in[4];
  const float* Kds  = (const float*)d_in[5];
  const float* fcor = (const float*)d_in[6];

  char* ws = (char*)d_ws;
  size_t pos = 0;
  auto carve = [&](size_t bytes) -> void* {
    void* p = ws + pos;
    pos += (bytes + 255) & ~(size_t)255;
    return p;
  };

  int*   jlo_a   = (int*)carve(sizeof(int) * NROWS);
  int*   cnt_a   = (int*)carve(sizeof(int) * NROWS);
  int*   off_a   = (int*)carve(sizeof(int) * NROWS);
  int4*  rowmeta = (int4*)carve(sizeof(int4) * NROWS);
  float* X1      = (float*)carve(sizeof(float) * 3 * (size_t)HVOL);
  float* X2      = (float*)carve(sizeof(float) * 3 * (size_t)HVOL);
  float* X3      = (float*)carve(sizeof(float) * 3 * (size_t)HVOL);
  float4* tapw   = (float4*)carve(sizeof(float4) * (size_t)TAPCAP);

  float* X1h = X1;  float* X1uv = X1 + HVOL;
  float* X2h = X2;  float* X2uv = X2 + HVOL;
  float* X3h = X3;  float* X3uv = X3 + HVOL;
  float* out_h  = (float*)d_out;          // [NB,1,NLAT,NLON]
  float* out_uv = (float*)d_out + HVOL;   // [NB,1,NLAT,NLON,2]

  support_kernel<<<NROWS, 64, 0, stream>>>(Kgc, Kgs, Kdc, Kds, jlo_a, cnt_a);
  scan_kernel<<<1, 256, 0, stream>>>(cnt_a, jlo_a, off_a, rowmeta, TAPCAP);
  fill_kernel<<<NROWS, 64, 0, stream>>>(Kgc, Kgs, Kdc, Kds, jlo_a, cnt_a, off_a,
                                        tapw, TAPCAP);

  dim3 gl(2, (NLAT - NHL) * NB);          // 2 x 2852
  dim3 gh(6, NHL * NB);                   // 6 x 32

  // stage 1: k1 from S0; X1 = S0 + dt/2 k1
  heavy_kernel<<<gh, HBT, 0, stream>>>(h0, uv0, h0, uv0, h0, uv0, h0, uv0, fcor,
                                       rowmeta, tapw, X1h, X1uv, 0.5f * DTSTEP, 0);
  light_kernel<<<gl, LBT, 0, stream>>>(h0, uv0, h0, uv0, h0, uv0, h0, uv0, fcor,
                                       rowmeta, tapw, X1h, X1uv, 0.5f * DTSTEP, 0);
  // stage 2: k2 from X1; X2 = S0 + dt/2 k2
  heavy_kernel<<<gh, HBT, 0, stream>>>(X1h, X1uv, h0, uv0, h0, uv0, h0, uv0, fcor,
                                       rowmeta, tapw, X2h, X2uv, 0.5f * DTSTEP, 0);
  light_kernel<<<gl, LBT, 0, stream>>>(X1h, X1uv, h0, uv0, h0, uv0, h0, uv0, fcor,
                                       rowmeta, tapw, X2h, X2uv, 0.5f * DTSTEP, 0);
  // stage 3: k3 from X2; X3 = S0 + dt k3
  heavy_kernel<<<gh, HBT, 0, stream>>>(X2h, X2uv, h0, uv0, h0, uv0, h0, uv0, fcor,
                                       rowmeta, tapw, X3h, X3uv, DTSTEP, 0);
  light_kernel<<<gl, LBT, 0, stream>>>(X2h, X2uv, h0, uv0, h0, uv0, h0, uv0, fcor,
                                       rowmeta, tapw, X3h, X3uv, DTSTEP, 0);
  // stage 4: k4 from X3; out = (X1 + 2 X2 + X3 - S0)/3 + dt/6 k4
  heavy_kernel<<<gh, HBT, 0, stream>>>(X3h, X3uv, h0, uv0, X1h, X1uv, X2h, X2uv, fcor,
                                       rowmeta, tapw, out_h, out_uv, 0.0f, 1);
  light_kernel<<<gl, LBT, 0, stream>>>(X3h, X3uv, h0, uv0, X1h, X1uv, X2h, X2uv, fcor,
                                       rowmeta, tapw, out_h, out_uv, 0.0f, 1);
}

// Round 9
// 499.732 us; speedup vs baseline: 2.4196x; 1.7466x over previous
//
#include <hip/hip_runtime.h>

#define NLAT 721
#define NLON 1440
#define NB 4
#define ND 5
#define NROWS (NLAT*ND)          // 3605
#define PLANE (NLAT*NLON)        // 1,038,240
#define HVOL (NB*PLANE)          // 4,152,960
#define DTSTEP 0.01f
#define TAPCAP 262144

// ---- fused kernel geometry ----
#define FBT 512                  // uniform block: 8 waves

// heavy sub-grid: lats {0..3, 717..720} x 4 batch x 6 col-tiles = 192 blocks
#define NHBLK 192
#define HNW 8
#define HNC 240                  // cols per heavy tile
#define HCHK 64                  // taps per wave-chunk
#define HW 1712                  // window floats per field (1682 + swizzle margin)
#define SMF 5760                 // smem floats: max(3*HW=5136 window, 8*720 combine)

// light sub-grid: lats 4..716 x 4 batch = 2852 blocks (full 1440-col rows)
#define NLL 713
#define LACT 360                 // act threads x 4 cols = 1440
#define LTC 240                  // taps per chunk (light rows: cnt <= 232 -> 1 chunk)
#define LW 1712                  // window floats per field (1680 + swizzle margin)

// ---------------------------------------------------------------------------
// Kernel A: per (lat,d) row, find the wrapped-interval support [jlo, jhi]
// ---------------------------------------------------------------------------
__global__ __launch_bounds__(64) void support_kernel(
    const float* __restrict__ Kgc, const float* __restrict__ Kgs,
    const float* __restrict__ Kdc, const float* __restrict__ Kds,
    int* __restrict__ jlo_a, int* __restrict__ cnt_a)
{
  int row = blockIdx.x;
  int lane = threadIdx.x;
  const float* a = Kgc + (size_t)row * NLON;
  const float* b = Kgs + (size_t)row * NLON;
  const float* c = Kdc + (size_t)row * NLON;
  const float* d = Kds + (size_t)row * NLON;
  int jmin = 1 << 30, jmax = -(1 << 30);
  for (int m = lane; m < NLON; m += 64) {
    float s = fabsf(a[m]) + fabsf(b[m]) + fabsf(c[m]) + fabsf(d[m]);
    if (s != 0.0f) {
      int j = (m >= NLON / 2) ? (m - NLON) : m;
      jmin = min(jmin, j);
      jmax = max(jmax, j);
    }
  }
  for (int s = 32; s > 0; s >>= 1) {
    jmin = min(jmin, __shfl_down(jmin, s));
    jmax = max(jmax, __shfl_down(jmax, s));
  }
  if (lane == 0) {
    if (jmax < jmin) { jlo_a[row] = 0; cnt_a[row] = 0; }
    else             { jlo_a[row] = jmin; cnt_a[row] = jmax - jmin + 1; }
  }
}

// ---------------------------------------------------------------------------
// Kernel B: prefix sum over 4-padded row counts; per-row meta
// int4(iq*NLON, jlo (signed), cnt4, pool offset).
// ---------------------------------------------------------------------------
__global__ __launch_bounds__(256) void scan_kernel(
    const int* __restrict__ cnt_a, const int* __restrict__ jlo_a,
    int* __restrict__ off_a, int4* __restrict__ rowmeta, int tap_cap)
{
  __shared__ int buf[256];
  __shared__ int carry;
  int tid = threadIdx.x;
  if (tid == 0) carry = 0;
  __syncthreads();
  for (int base = 0; base < NROWS; base += 256) {
    int i = base + tid;
    int v = (i < NROWS) ? ((cnt_a[i] + 3) & ~3) : 0;
    buf[tid] = v;
    __syncthreads();
    for (int s = 1; s < 256; s <<= 1) {
      int t = (tid >= s) ? buf[tid - s] : 0;
      __syncthreads();
      buf[tid] += t;
      __syncthreads();
    }
    if (i < NROWS) off_a[i] = carry + buf[tid] - v;   // exclusive
    __syncthreads();
    if (tid == 255) carry += buf[255];
    __syncthreads();
  }
  __syncthreads();
  for (int r = tid; r < NROWS; r += 256) {
    int off = off_a[r];
    int c4  = (cnt_a[r] + 3) & ~3;
    if (off >= tap_cap)           c4 = 0;
    else if (off + c4 > tap_cap)  c4 = (tap_cap - off) & ~3;
    int l = r / ND, d = r - ND * l;
    int iq = min(max(l + d - 2, 0), NLAT - 1);
    rowmeta[r] = make_int4(iq * NLON, jlo_a[r], c4, off);
  }
}

// ---------------------------------------------------------------------------
// Kernel C: fill weight pool (Kg_c, Kg_s, Kd_c, Kd_s), zero-padded to x4.
// ---------------------------------------------------------------------------
__global__ __launch_bounds__(64) void fill_kernel(
    const float* __restrict__ Kgc, const float* __restrict__ Kgs,
    const float* __restrict__ Kdc, const float* __restrict__ Kds,
    const int* __restrict__ jlo_a, const int* __restrict__ cnt_a,
    const int* __restrict__ off_a,
    float4* __restrict__ tapw, int tap_cap)
{
  int row = blockIdx.x;
  int jlo = jlo_a[row], cnt = cnt_a[row], off = off_a[row];
  int cnt4 = (cnt + 3) & ~3;
  for (int t = threadIdx.x; t < cnt4; t += 64) {
    int p = off + t;
    if (p >= tap_cap) break;
    float4 w = make_float4(0.f, 0.f, 0.f, 0.f);
    if (t < cnt) {
      int j = jlo + t;
      int m = j + ((j < 0) ? NLON : 0);
      size_t idx = (size_t)row * NLON + m;
      w = make_float4(Kgc[idx], Kgs[idx], Kdc[idx], Kds[idx]);
    }
    tapw[p] = w;
  }
}

// ---------------------------------------------------------------------------
// Shared epilogue: Coriolis + RK4 combine for 4 consecutive columns at ih.
// mode 0: O = S0 + cdt*k ; mode 1: O = (X1+2*X2+X3-S0)/3 + (DT/6)*k4
// ---------------------------------------------------------------------------
__device__ __forceinline__ void rk4_epilogue(
    float ah0, float ah1, float ah2, float ah3,
    float au0, float au1, float au2, float au3,
    float av0, float av1, float av2, float av3,
    size_t ih, float f,
    const float* __restrict__ Xh,  const float* __restrict__ Xuv,
    const float* __restrict__ S0h, const float* __restrict__ S0uv,
    const float* __restrict__ X1h, const float* __restrict__ X1uv,
    const float* __restrict__ X2h, const float* __restrict__ X2uv,
    float* __restrict__ Oh, float* __restrict__ Ouv,
    float cdt, int mode)
{
  size_t iuv = 2 * ih;
  float4 xa = *(const float4*)(Xuv + iuv);      // u0,v0,u1,v1
  float4 xb = *(const float4*)(Xuv + iuv + 4);  // u2,v2,u3,v3
  float kh0 = -ah0, kh1 = -ah1, kh2 = -ah2, kh3 = -ah3;
  float ku0 = fmaf(-f, xa.y, -au0), kv0 = fmaf(f, xa.x, -av0);
  float ku1 = fmaf(-f, xa.w, -au1), kv1 = fmaf(f, xa.z, -av1);
  float ku2 = fmaf(-f, xb.y, -au2), kv2 = fmaf(f, xb.x, -av2);
  float ku3 = fmaf(-f, xb.w, -au3), kv3 = fmaf(f, xb.z, -av3);

  if (mode == 0) {
    float4 s0 = *(const float4*)(S0h + ih);
    *(float4*)(Oh + ih) = make_float4(fmaf(cdt, kh0, s0.x), fmaf(cdt, kh1, s0.y),
                                      fmaf(cdt, kh2, s0.z), fmaf(cdt, kh3, s0.w));
    float4 sa = *(const float4*)(S0uv + iuv);
    float4 sb = *(const float4*)(S0uv + iuv + 4);
    *(float4*)(Ouv + iuv)     = make_float4(fmaf(cdt, ku0, sa.x), fmaf(cdt, kv0, sa.y),
                                            fmaf(cdt, ku1, sa.z), fmaf(cdt, kv1, sa.w));
    *(float4*)(Ouv + iuv + 4) = make_float4(fmaf(cdt, ku2, sb.x), fmaf(cdt, kv2, sb.y),
                                            fmaf(cdt, ku3, sb.z), fmaf(cdt, kv3, sb.w));
  } else {
    const float DT6 = DTSTEP / 6.0f;
    const float TH  = 1.0f / 3.0f;
    float4 xh3 = *(const float4*)(Xh + ih);   // X3 h at own cols
    float4 s0 = *(const float4*)(S0h + ih);
    float4 x1 = *(const float4*)(X1h + ih);
    float4 x2 = *(const float4*)(X2h + ih);
    *(float4*)(Oh + ih) = make_float4(
      TH * (x1.x + 2.f * x2.x + xh3.x - s0.x) + DT6 * kh0,
      TH * (x1.y + 2.f * x2.y + xh3.y - s0.y) + DT6 * kh1,
      TH * (x1.z + 2.f * x2.z + xh3.z - s0.z) + DT6 * kh2,
      TH * (x1.w + 2.f * x2.w + xh3.w - s0.w) + DT6 * kh3);
    float4 sa = *(const float4*)(S0uv + iuv);
    float4 sb = *(const float4*)(S0uv + iuv + 4);
    float4 xa1 = *(const float4*)(X1uv + iuv);
    float4 xb1 = *(const float4*)(X1uv + iuv + 4);
    float4 xa2 = *(const float4*)(X2uv + iuv);
    float4 xb2 = *(const float4*)(X2uv + iuv + 4);
    *(float4*)(Ouv + iuv) = make_float4(
      TH * (xa1.x + 2.f * xa2.x + xa.x - sa.x) + DT6 * ku0,
      TH * (xa1.y + 2.f * xa2.y + xa.y - sa.y) + DT6 * kv0,
      TH * (xa1.z + 2.f * xa2.z + xa.z - sa.z) + DT6 * ku1,
      TH * (xa1.w + 2.f * xa2.w + xa.w - sa.w) + DT6 * kv1);
    *(float4*)(Ouv + iuv + 4) = make_float4(
      TH * (xb1.x + 2.f * xb2.x + xb.x - sb.x) + DT6 * ku2,
      TH * (xb1.y + 2.f * xb2.y + xb.y - sb.y) + DT6 * kv2,
      TH * (xb1.z + 2.f * xb2.z + xb.z - sb.z) + DT6 * ku3,
      TH * (xb1.w + 2.f * xb2.w + xb.w - sb.w) + DT6 * kv3);
  }
}

// 16B-block XOR swizzle (verified r4/r6/r8): dword bits[4:2] ^= bits[8:6];
// preserves float4 contiguity, spreads stride-16B lane patterns across banks.
__device__ __forceinline__ int swz(int d) { return d ^ ((d >> 4) & 28); }
__device__ __forceinline__ float4 ldswz(const float* base, int o) {
  return *(const float4*)(base + swz(o));
}

// 16 FMAs for one tap (weights W), elements a..d per column 0..3
#define TAP(W, a, b, c, d)                                                   \
  ah0 = fmaf(W.z, U##a, ah0); ah0 = fmaf(W.w, V##a, ah0);                    \
  au0 = fmaf(W.x, H##a, au0); av0 = fmaf(W.y, H##a, av0);                    \
  ah1 = fmaf(W.z, U##b, ah1); ah1 = fmaf(W.w, V##b, ah1);                    \
  au1 = fmaf(W.x, H##b, au1); av1 = fmaf(W.y, H##b, av1);                    \
  ah2 = fmaf(W.z, U##c, ah2); ah2 = fmaf(W.w, V##c, ah2);                    \
  au2 = fmaf(W.x, H##c, au2); av2 = fmaf(W.y, H##c, av2);                    \
  ah3 = fmaf(W.z, U##d, ah3); ah3 = fmaf(W.w, V##d, ah3);                    \
  au3 = fmaf(W.x, H##d, au3); av3 = fmaf(W.y, H##d, av3);

#define GROUP4()                                                             \
  {                                                                          \
    float H0 = Ha.x, H1 = Ha.y, H2 = Ha.z, H3 = Ha.w;                        \
    float H4 = Hb.x, H5 = Hb.y, H6 = Hb.z;                                   \
    float U0 = Ua.x, U1 = Ua.y, U2 = Ua.z, U3 = Ua.w;                        \
    float U4 = Ub.x, U5 = Ub.y, U6 = Ub.z;                                   \
    float V0 = Va.x, V1 = Va.y, V2 = Va.z, V3 = Va.w;                        \
    float V4 = Vb.x, V5 = Vb.y, V6 = Vb.z;                                   \
    TAP(W0, 0, 1, 2, 3)                                                      \
    TAP(W1, 1, 2, 3, 4)                                                      \
    TAP(W2, 2, 3, 4, 5)                                                      \
    TAP(W3, 3, 4, 5, 6)                                                      \
    Ha = Hb; Ua = Ub; Va = Vb;                                               \
  }

// ---------------------------------------------------------------------------
// FUSED stage kernel.  Uniform 512-thread blocks, 23 KB LDS (4 blocks/CU =
// 32 waves).  blockIdx.x < 192: HEAVY path (lats {0..3,717..720} x 4b x 6
// col-tiles; 8 waves stride 64-tap chunks of a shared staged window; LDS
// combine; no atomics) — dispatched FIRST so its long tap loops overlap the
// light wave.  Else: LIGHT path (lats 4..716 x 4b, full 1440-col row, 360 act
// threads; stage row window once, rolling-float4 tap loop, weights straight
// from global via readfirstlane-uniform address).
// ---------------------------------------------------------------------------
__global__ __launch_bounds__(FBT, 4) void stage_fused(
    const float* __restrict__ Xh,  const float* __restrict__ Xuv,
    const float* __restrict__ S0h, const float* __restrict__ S0uv,
    const float* __restrict__ X1h, const float* __restrict__ X1uv,
    const float* __restrict__ X2h, const float* __restrict__ X2uv,
    const float* __restrict__ fcor,
    const int4* __restrict__ rowmeta, const float4* __restrict__ tapw,
    float* __restrict__ Oh, float* __restrict__ Ouv,
    float cdt, int mode)
{
  __shared__ __align__(16) float smem[SMF];
  float* __restrict__ sh = smem;
  int tid = threadIdx.x;
  int bx = blockIdx.x;

  if (bx < NHBLK) {
    // ================= HEAVY path =================
    float* __restrict__ su = smem + HW;
    float* __restrict__ sv = smem + 2 * HW;
    int tile = bx % 6;
    int pr   = bx / 6;                        // 0..31
    int lh = pr >> 2, b = pr & 3;
    int l  = (lh < 4) ? lh : (713 + lh);      // 0..3, 717..720
    int c0 = tile * HNC;
    int wv = tid >> 6, lane = tid & 63;
    bool act = lane < 60;
    int w = 4 * lane;

    const float* __restrict__ xh  = Xh  + (size_t)b * PLANE;
    const float* __restrict__ xuv = Xuv + (size_t)b * PLANE * 2;

    float ah0 = 0.f, ah1 = 0.f, ah2 = 0.f, ah3 = 0.f;
    float au0 = 0.f, au1 = 0.f, au2 = 0.f, au3 = 0.f;
    float av0 = 0.f, av1 = 0.f, av2 = 0.f, av3 = 0.f;

    for (int d = 0; d < ND; ++d) {
      int4 rm = rowmeta[l * ND + d];          // uniform
      int cnt = rm.z;
      if (cnt == 0) continue;
      const float* __restrict__ grh  = xh  + rm.x;
      const float* __restrict__ gruv = xuv + 2 * (size_t)rm.x;

      int wlen = HNC - 1 + cnt + 3;           // <= 1682
      int gg = c0 + rm.y;
      gg %= NLON; if (gg < 0) gg += NLON;

      __syncthreads();                        // prior row's readers done
      for (int e = tid; e < wlen; e += FBT) {
        int g = gg + e;                       // < 1440 + 1682
        g -= (g >= NLON) ? NLON : 0;
        g -= (g >= NLON) ? NLON : 0;
        float  hh = grh[g];
        float2 uv = *(const float2*)(gruv + 2 * g);
        int se = swz(e);
        sh[se] = hh; su[se] = uv.x; sv[se] = uv.y;
      }
      __syncthreads();                        // window staged

      if (act) {
        int nch = (cnt + HCHK - 1) / HCHK;
        for (int cc = wv; cc < nch; cc += HNW) {
          int tb = cc * HCHK;
          int twcnt = min(HCHK, cnt - tb);    // multiple of 4
          int wb = __builtin_amdgcn_readfirstlane(rm.w + tb);
          int o0 = w + tb;
          float4 Ha = ldswz(sh, o0), Ua = ldswz(su, o0), Va = ldswz(sv, o0);
          for (int tg = 0; tg < twcnt; tg += 4) {
            float4 W0 = tapw[wb + tg],     W1 = tapw[wb + tg + 1];
            float4 W2 = tapw[wb + tg + 2], W3 = tapw[wb + tg + 3];
            float4 Hb = ldswz(sh, o0 + tg + 4);
            float4 Ub = ldswz(su, o0 + tg + 4);
            float4 Vb = ldswz(sv, o0 + tg + 4);
            GROUP4()
          }
        }
      }
    }

    // ---- cross-wave combine (reuse smem; all compute reads done) ----
    __syncthreads();
    if (act) {
      float* cs = smem + wv * 720;
      *(float4*)(cs + w)       = make_float4(ah0, ah1, ah2, ah3);
      *(float4*)(cs + 240 + w) = make_float4(au0, au1, au2, au3);
      *(float4*)(cs + 480 + w) = make_float4(av0, av1, av2, av3);
    }
    __syncthreads();

    if (tid < 60) {
      int c4 = 4 * tid;
      float h0 = 0.f, h1 = 0.f, h2 = 0.f, h3 = 0.f;
      float u0 = 0.f, u1 = 0.f, u2 = 0.f, u3 = 0.f;
      float v0 = 0.f, v1 = 0.f, v2 = 0.f, v3 = 0.f;
#pragma unroll
      for (int t = 0; t < HNW; ++t) {
        const float* cs = smem + t * 720;
        float4 A = *(const float4*)(cs + c4);
        float4 B = *(const float4*)(cs + 240 + c4);
        float4 C = *(const float4*)(cs + 480 + c4);
        h0 += A.x; h1 += A.y; h2 += A.z; h3 += A.w;
        u0 += B.x; u1 += B.y; u2 += B.z; u3 += B.w;
        v0 += C.x; v1 += C.y; v2 += C.z; v3 += C.w;
      }
      size_t ih = (size_t)b * PLANE + (size_t)l * NLON + c0 + c4;
      rk4_epilogue(h0, h1, h2, h3, u0, u1, u2, u3, v0, v1, v2, v3,
                   ih, fcor[l], Xh, Xuv, S0h, S0uv, X1h, X1uv, X2h, X2uv,
                   Oh, Ouv, cdt, mode);
    }
  } else {
    // ================= LIGHT path =================
    float* __restrict__ su = smem + LW;
    float* __restrict__ sv = smem + 2 * LW;
    int idx = bx - NHBLK;
    int li = idx >> 2;                        // 0..712
    int b  = idx & 3;
    int l  = (li & 1) ? (716 - (li >> 1)) : (4 + (li >> 1));  // both ends first
    bool act = tid < LACT;
    int w = 4 * tid;

    const float* __restrict__ xh  = Xh  + (size_t)b * PLANE;
    const float* __restrict__ xuv = Xuv + (size_t)b * PLANE * 2;

    float ah0 = 0.f, ah1 = 0.f, ah2 = 0.f, ah3 = 0.f;
    float au0 = 0.f, au1 = 0.f, au2 = 0.f, au3 = 0.f;
    float av0 = 0.f, av1 = 0.f, av2 = 0.f, av3 = 0.f;

    for (int d = 0; d < ND; ++d) {
      int4 rm = rowmeta[l * ND + d];          // uniform
      int cnt = rm.z;
      if (cnt == 0) continue;
      const float* __restrict__ grh  = xh  + rm.x;
      const float* __restrict__ gruv = xuv + 2 * (size_t)rm.x;

      for (int tc = 0; tc < cnt; tc += LTC) {
        int wcnt = min(LTC, cnt - tc);        // multiple of 4
        int wlen = NLON + wcnt;               // indices 0 .. 1439+wcnt
        int gg = rm.y + tc;
        gg %= NLON; if (gg < 0) gg += NLON;

        __syncthreads();                      // prior chunk's readers done
        for (int e = tid; e < wlen; e += FBT) {
          int g = gg + e;                     // < 1440 + 1680
          g -= (g >= NLON) ? NLON : 0;
          g -= (g >= NLON) ? NLON : 0;
          float  hh = grh[g];
          float2 uv = *(const float2*)(gruv + 2 * g);
          int se = swz(e);
          sh[se] = hh; su[se] = uv.x; sv[se] = uv.y;
        }
        __syncthreads();

        if (act) {
          int wb = __builtin_amdgcn_readfirstlane(rm.w + tc);
          float4 Ha = ldswz(sh, w), Ua = ldswz(su, w), Va = ldswz(sv, w);
          for (int tg = 0; tg < wcnt; tg += 4) {
            float4 W0 = tapw[wb + tg],     W1 = tapw[wb + tg + 1];
            float4 W2 = tapw[wb + tg + 2], W3 = tapw[wb + tg + 3];
            float4 Hb = ldswz(sh, w + tg + 4);
            float4 Ub = ldswz(su, w + tg + 4);
            float4 Vb = ldswz(sv, w + tg + 4);
            GROUP4()
          }
        }
      }
    }

    if (act) {
      size_t ih = (size_t)b * PLANE + (size_t)l * NLON + w;
      rk4_epilogue(ah0, ah1, ah2, ah3, au0, au1, au2, au3, av0, av1, av2, av3,
                   ih, fcor[l], Xh, Xuv, S0h, S0uv, X1h, X1uv, X2h, X2uv,
                   Oh, Ouv, cdt, mode);
    }
  }
}

// ---------------------------------------------------------------------------
extern "C" void kernel_launch(void* const* d_in, const int* in_sizes, int n_in,
                              void* d_out, int out_size, void* d_ws, size_t ws_size,
                              hipStream_t stream)
{
  const float* h0   = (const float*)d_in[0];
  const float* uv0  = (const float*)d_in[1];
  const float* Kgc  = (const float*)d_in[2];
  const float* Kgs  = (const float*)d_in[3];
  const float* Kdc  = (const float*)d_in[4];
  const float* Kds  = (const float*)d_in[5];
  const float* fcor = (const float*)d_in[6];

  char* ws = (char*)d_ws;
  size_t pos = 0;
  auto carve = [&](size_t bytes) -> void* {
    void* p = ws + pos;
    pos += (bytes + 255) & ~(size_t)255;
    return p;
  };

  int*   jlo_a   = (int*)carve(sizeof(int) * NROWS);
  int*   cnt_a   = (int*)carve(sizeof(int) * NROWS);
  int*   off_a   = (int*)carve(sizeof(int) * NROWS);
  int4*  rowmeta = (int4*)carve(sizeof(int4) * NROWS);
  float* X1      = (float*)carve(sizeof(float) * 3 * (size_t)HVOL);
  float* X2      = (float*)carve(sizeof(float) * 3 * (size_t)HVOL);
  float* X3      = (float*)carve(sizeof(float) * 3 * (size_t)HVOL);
  float4* tapw   = (float4*)carve(sizeof(float4) * (size_t)TAPCAP);

  float* X1h = X1;  float* X1uv = X1 + HVOL;
  float* X2h = X2;  float* X2uv = X2 + HVOL;
  float* X3h = X3;  float* X3uv = X3 + HVOL;
  float* out_h  = (float*)d_out;          // [NB,1,NLAT,NLON]
  float* out_uv = (float*)d_out + HVOL;   // [NB,1,NLAT,NLON,2]

  support_kernel<<<NROWS, 64, 0, stream>>>(Kgc, Kgs, Kdc, Kds, jlo_a, cnt_a);
  scan_kernel<<<1, 256, 0, stream>>>(cnt_a, jlo_a, off_a, rowmeta, TAPCAP);
  fill_kernel<<<NROWS, 64, 0, stream>>>(Kgc, Kgs, Kdc, Kds, jlo_a, cnt_a, off_a,
                                        tapw, TAPCAP);

  dim3 gs(NHBLK + NLL * NB);              // 192 heavy + 2852 light

  // stage 1: k1 from S0; X1 = S0 + dt/2 k1
  stage_fused<<<gs, FBT, 0, stream>>>(h0, uv0, h0, uv0, h0, uv0, h0, uv0, fcor,
                                      rowmeta, tapw, X1h, X1uv, 0.5f * DTSTEP, 0);
  // stage 2: k2 from X1; X2 = S0 + dt/2 k2
  stage_fused<<<gs, FBT, 0, stream>>>(X1h, X1uv, h0, uv0, h0, uv0, h0, uv0, fcor,
                                      rowmeta, tapw, X2h, X2uv, 0.5f * DTSTEP, 0);
  // stage 3: k3 from X2; X3 = S0 + dt k3
  stage_fused<<<gs, FBT, 0, stream>>>(X2h, X2uv, h0, uv0, h0, uv0, h0, uv0, fcor,
                                      rowmeta, tapw, X3h, X3uv, DTSTEP, 0);
  // stage 4: k4 from X3; out = (X1 + 2 X2 + X3 - S0)/3 + dt/6 k4
  stage_fused<<<gs, FBT, 0, stream>>>(X3h, X3uv, h0, uv0, X1h, X1uv, X2h, X2uv, fcor,
                                      rowmeta, tapw, out_h, out_uv, 0.0f, 1);
}